// Round 6
// baseline (785.829 us; speedup 1.0000x reference)
//
#include <hip/hip_runtime.h>
#include <stdint.h>

// ---------- types ----------
typedef __attribute__((ext_vector_type(8))) short short8;
typedef __attribute__((ext_vector_type(4))) float floatx4;

__device__ inline float bf2f(unsigned short u) {
  union { unsigned int i; float f; } v; v.i = ((unsigned int)u) << 16; return v.f;
}
__device__ inline unsigned short f2bf(float f) {
  union { float f; unsigned int i; } v; v.f = f;
  unsigned int r = v.i + 0x7FFFu + ((v.i >> 16) & 1u);  // round-nearest-even
  return (unsigned short)(r >> 16);
}

// ---------- utility ----------
__global__ void zero_i32(int* __restrict__ p, int n) {
  int i = blockIdx.x * blockDim.x + threadIdx.x;
  if (i < n) p[i] = 0;
}

// f32 -> bf16 row conversion (x -> xb)
__global__ void cvt_bf16(const float* __restrict__ x, unsigned short* __restrict__ xb, int n) {
  int i = blockIdx.x * blockDim.x + threadIdx.x;
  if (i < n) xb[i] = f2bf(x[i]);
}

// count per (dst,rel): one int atomic per edge
__global__ void count_rel(const int* __restrict__ dst, const int* __restrict__ et,
                          int* __restrict__ cnt, int E) {
  int e = blockIdx.x * blockDim.x + threadIdx.x;
  if (e < E) atomicAdd(&cnt[(size_t)dst[e] * 8 + et[e]], 1);
}

// ---------- exclusive scan of cnt[n] -> eptr[n] (+eptr[n]=E), epos copy ----------
#define SCAN_T 256
#define SCAN_E 16   // 4096 elems per block -> 196 blocks for n=800k

__global__ void scan1(const int* __restrict__ cnt, int* __restrict__ bsum, int n) {
  __shared__ int lds[SCAN_T];
  int base = blockIdx.x * (SCAN_T * SCAN_E);
  int tid = threadIdx.x;
  int s = 0;
#pragma unroll
  for (int j = 0; j < SCAN_E; ++j) {
    int i = base + tid * SCAN_E + j;
    if (i < n) s += cnt[i];
  }
  lds[tid] = s; __syncthreads();
  for (int off = SCAN_T / 2; off > 0; off >>= 1) {
    if (tid < off) lds[tid] += lds[tid + off];
    __syncthreads();
  }
  if (tid == 0) bsum[blockIdx.x] = lds[0];
}

__global__ void scan2(int* __restrict__ bsum, int* __restrict__ eptr, int nb, int n) {
  if (threadIdx.x == 0 && blockIdx.x == 0) {
    int run = 0;
    for (int b = 0; b < nb; ++b) { int v = bsum[b]; bsum[b] = run; run += v; }
    eptr[n] = run;
  }
}

__global__ void scan3(const int* __restrict__ cnt, const int* __restrict__ bsum,
                      int* __restrict__ eptr, int* __restrict__ epos, int n) {
  __shared__ int lds[SCAN_T];
  int base = blockIdx.x * (SCAN_T * SCAN_E);
  int tid = threadIdx.x;
  int loc[SCAN_E]; int s = 0;
#pragma unroll
  for (int j = 0; j < SCAN_E; ++j) {
    int i = base + tid * SCAN_E + j;
    loc[j] = (i < n) ? cnt[i] : 0; s += loc[j];
  }
  lds[tid] = s; __syncthreads();
  for (int off = 1; off < SCAN_T; off <<= 1) {   // Hillis-Steele inclusive
    int v = (tid >= off) ? lds[tid - off] : 0;
    __syncthreads();
    lds[tid] += v;
    __syncthreads();
  }
  int run = (tid > 0 ? lds[tid - 1] : 0) + bsum[blockIdx.x];
#pragma unroll
  for (int j = 0; j < SCAN_E; ++j) {
    int i = base + tid * SCAN_E + j;
    if (i < n) { eptr[i] = run; epos[i] = run; run += loc[j]; }
  }
}

// scatter edges into (dst,rel)-sorted order; entry = src
__global__ void scatter_edges(const int* __restrict__ src, const int* __restrict__ dst,
                              const int* __restrict__ et, int* __restrict__ epos,
                              int* __restrict__ entry, int E) {
  int e = blockIdx.x * blockDim.x + threadIdx.x;
  if (e < E) {
    int p = atomicAdd(&epos[(size_t)dst[e] * 8 + et[e]], 1);
    entry[p] = src[e];
  }
}

// ---------- aggregation: one wave per dst node.
// meanb[d][r][lane] = mean over segment (d,r) of xb[src][lane]  (bf16 out, no atomics)
__global__ void __launch_bounds__(256)
agg(const unsigned short* __restrict__ xb, const int* __restrict__ eptr,
    const int* __restrict__ entry, unsigned short* __restrict__ meanb, int N)
{
  const int wid  = (blockIdx.x * blockDim.x + threadIdx.x) >> 6;
  const int lane = threadIdx.x & 63;
  if (wid >= N) return;
  const int base = wid * 8;
  unsigned short* mr = meanb + (size_t)wid * 512;
  for (int r = 0; r < 8; ++r) {
    const int lo = eptr[base + r], hi = eptr[base + r + 1];
    float sum = 0.f;
    int e = lo;
    for (; e + 4 <= hi; e += 4) {
      int s0 = entry[e], s1 = entry[e + 1], s2 = entry[e + 2], s3 = entry[e + 3];
      sum += bf2f(xb[(size_t)s0 * 64 + lane]) + bf2f(xb[(size_t)s1 * 64 + lane])
           + bf2f(xb[(size_t)s2 * 64 + lane]) + bf2f(xb[(size_t)s3 * 64 + lane]);
    }
    for (; e < hi; ++e) sum += bf2f(xb[(size_t)entry[e] * 64 + lane]);
    float m = sum / (float)max(hi - lo, 1);
    mr[r * 64 + lane] = f2bf(m);
  }
}

// ---------- pre-pack W (8 mats) + root into MFMA B-fragment layout, bf16 ----------
// Wb[((mat*2+kc)*4+nt)*512 + lane*8 + j] = M[k][c], k=kc*32+(lane>>4)*8+j, c=nt*16+(lane&15)
__global__ void prep_wb(const float* __restrict__ W, const float* __restrict__ root,
                        unsigned short* __restrict__ Wb) {
  int idx = blockIdx.x * blockDim.x + threadIdx.x;  // 9*4096
  if (idx >= 9 * 4096) return;
  int j = idx & 7, lane = (idx >> 3) & 63, nt = (idx >> 9) & 3, kc = (idx >> 11) & 1, mat = idx >> 12;
  int k = kc * 32 + (lane >> 4) * 8 + j, c = nt * 16 + (lane & 15);
  float v = (mat < 8) ? W[((size_t)mat * 64 + k) * 64 + c] : root[(size_t)k * 64 + c];
  Wb[idx] = f2bf(v);
}

// ---------- fused einsum: out = sum_r mean_r @ W_r + x @ root + b  (K=576 via 18 MFMAs)
// relu_out: write relu(v) as bf16 (layer 1 -> hb); else f32 (layer 2 -> acc)
__global__ void __launch_bounds__(256)
mfma_pass(const unsigned short* __restrict__ meanb, const unsigned short* __restrict__ xb,
          const unsigned short* __restrict__ Wb, const float* __restrict__ bias,
          unsigned short* __restrict__ out_bf, float* __restrict__ out_f32,
          int N, int relu_out)
{
  const int lane = threadIdx.x & 63;
  const int wave = threadIdx.x >> 6;
  const int lc   = lane & 15;
  const int quad = lane >> 4;
  float bvs[4];
#pragma unroll
  for (int nt = 0; nt < 4; ++nt) bvs[nt] = bias[nt * 16 + lc];

  const int tiles  = (N + 15) >> 4;
  const int stride = gridDim.x * 4;
  for (int t = blockIdx.x * 4 + wave; t < tiles; t += stride) {
    const int nb  = t << 4;
    const int row = min(nb + lc, N - 1);
    const unsigned short* mr = meanb + (size_t)row * 512;
    const unsigned short* xr = xb + (size_t)row * 64;
    short8 am[9][2];
#pragma unroll
    for (int r = 0; r < 8; ++r) {
      am[r][0] = *(const short8*)(mr + r * 64 + quad * 8);
      am[r][1] = *(const short8*)(mr + r * 64 + 32 + quad * 8);
    }
    am[8][0] = *(const short8*)(xr + quad * 8);
    am[8][1] = *(const short8*)(xr + 32 + quad * 8);
#pragma unroll
    for (int nt = 0; nt < 4; ++nt) {
      floatx4 d = {0.f, 0.f, 0.f, 0.f};
#pragma unroll
      for (int mat = 0; mat < 9; ++mat) {
        short8 b0 = *(const short8*)(Wb + (size_t)((mat * 2 + 0) * 4 + nt) * 512 + lane * 8);
        short8 b1 = *(const short8*)(Wb + (size_t)((mat * 2 + 1) * 4 + nt) * 512 + lane * 8);
        d = __builtin_amdgcn_mfma_f32_16x16x32_bf16(am[mat][0], b0, d, 0, 0, 0);
        d = __builtin_amdgcn_mfma_f32_16x16x32_bf16(am[mat][1], b1, d, 0, 0, 0);
      }
      const int c = nt * 16 + lc;
#pragma unroll
      for (int i = 0; i < 4; ++i) {
        int r_ = nb + quad * 4 + i;
        if (r_ < N) {
          float v = d[i] + bvs[nt];
          if (relu_out) out_bf[(size_t)r_ * 64 + c] = f2bf(fmaxf(v, 0.f));
          else          out_f32[(size_t)r_ * 64 + c] = v;
        }
      }
    }
  }
}

// graph segment boundaries from sorted batch
__global__ void glo_bounds(const int* __restrict__ batch, int* __restrict__ glo,
                           int N, int G) {
  int g = blockIdx.x * blockDim.x + threadIdx.x;
  if (g > G) return;
  if (g == G) { glo[G] = N; return; }
  int lo = 0, hi = N;
  while (lo < hi) { int mid = (lo + hi) >> 1; if (batch[mid] < g) lo = mid + 1; else hi = mid; }
  glo[g] = lo;
}

// fused mean-pool + finalize: one block per graph, contiguous node segment
__global__ void __launch_bounds__(256)
pool(const float* __restrict__ acc, const int* __restrict__ glo,
     float* __restrict__ out, int G)
{
  const int g = blockIdx.x;
  const int lane = threadIdx.x & 63;
  const int w = threadIdx.x >> 6;
  const int lo = glo[g], hi = glo[g + 1];
  float s = 0.f;
  for (int n = lo + w; n < hi; n += 4) s += acc[(size_t)n * 64 + lane];
  __shared__ float red[4][64];
  red[w][lane] = s;
  __syncthreads();
  if (w == 0) {
    float t = red[0][lane] + red[1][lane] + red[2][lane] + red[3][lane];
    out[(size_t)g * 64 + lane] = t / fmaxf((float)(hi - lo), 1.0f);
  }
}

// ---------- launch ----------
extern "C" void kernel_launch(void* const* d_in, const int* in_sizes, int n_in,
                              void* d_out, int out_size, void* d_ws, size_t ws_size,
                              hipStream_t stream)
{
  const float* x     = (const float*)d_in[0];
  const int*   ei    = (const int*)d_in[1];
  const int*   etype = (const int*)d_in[2];
  const int*   batch = (const int*)d_in[3];
  const float* W1    = (const float*)d_in[4];
  const float* root1 = (const float*)d_in[5];
  const float* b1    = (const float*)d_in[6];
  const float* W2    = (const float*)d_in[7];
  const float* root2 = (const float*)d_in[8];
  const float* b2    = (const float*)d_in[9];

  const int N = in_sizes[0] / 64;
  const int E = in_sizes[1] / 2;
  const int G = out_size / 64;
  const int* srcp = ei;
  const int* dstp = ei + E;

  // workspace carve-up (256B aligned), ~170 MB total
  char* ws = (char*)d_ws;
  size_t off = 0;
  auto carve = [&](size_t bytes) -> void* {
    void* p = ws + off; off = (off + bytes + 255) & ~(size_t)255; return p;
  };
  unsigned short* xb    = (unsigned short*)carve((size_t)N * 64 * 2);
  unsigned short* hb    = (unsigned short*)carve((size_t)N * 64 * 2);
  unsigned short* meanb = (unsigned short*)carve((size_t)N * 512 * 2);
  float*          acc   = (float*)carve((size_t)N * 64 * 4);
  int*            cnt   = (int*)carve((size_t)N * 8 * 4);
  int*            eptr  = (int*)carve(((size_t)N * 8 + 1) * 4);
  int*            epos  = (int*)carve((size_t)N * 8 * 4);
  int*            entry = (int*)carve((size_t)E * 4);
  unsigned short* Wb1   = (unsigned short*)carve((size_t)9 * 4096 * 2);
  unsigned short* Wb2   = (unsigned short*)carve((size_t)9 * 4096 * 2);
  int*            bsum  = (int*)carve(1024 * 4);
  int*            glo   = (int*)carve((size_t)(G + 1) * 4);
  (void)ws_size; (void)n_in;

  const int nseg = N * 8;
  const int nb_scan = (nseg + SCAN_T * SCAN_E - 1) / (SCAN_T * SCAN_E);
  const int nh = N * 64;

  // ---- CSR build by (dst,rel) ----
  zero_i32<<<(nseg + 255) / 256, 256, 0, stream>>>(cnt, nseg);
  count_rel<<<(E + 255) / 256, 256, 0, stream>>>(dstp, etype, cnt, E);
  scan1<<<nb_scan, SCAN_T, 0, stream>>>(cnt, bsum, nseg);
  scan2<<<1, 64, 0, stream>>>(bsum, eptr, nb_scan, nseg);
  scan3<<<nb_scan, SCAN_T, 0, stream>>>(cnt, bsum, eptr, epos, nseg);
  scatter_edges<<<(E + 255) / 256, 256, 0, stream>>>(srcp, dstp, etype, epos, entry, E);

  // ---- prep ----
  cvt_bf16<<<(nh + 255) / 256, 256, 0, stream>>>(x, xb, nh);
  prep_wb<<<(9 * 4096 + 255) / 256, 256, 0, stream>>>(W1, root1, Wb1);
  prep_wb<<<(9 * 4096 + 255) / 256, 256, 0, stream>>>(W2, root2, Wb2);
  glo_bounds<<<1, 128, 0, stream>>>(batch, glo, N, G);

  const int aggBlocks = (N * 64 + 255) / 256;

  // ---- layer 1: aggregate x then transform (relu fused, bf16 h out) ----
  agg<<<aggBlocks, 256, 0, stream>>>(xb, eptr, entry, meanb, N);
  mfma_pass<<<512, 256, 0, stream>>>(meanb, xb, Wb1, b1, hb, (float*)nullptr, N, 1);

  // ---- layer 2: aggregate h then transform (f32 out for pool) ----
  agg<<<aggBlocks, 256, 0, stream>>>(hb, eptr, entry, meanb, N);
  mfma_pass<<<512, 256, 0, stream>>>(meanb, hb, Wb2, b2, (unsigned short*)nullptr, acc, N, 0);

  // ---- global mean pool ----
  pool<<<G, 256, 0, stream>>>(acc, glo, (float*)d_out, G);
}